// Round 4
// 498.981 us; speedup vs baseline: 1.0750x; 1.0750x over previous
//
#include <hip/hip_runtime.h>
#include <hip/hip_bf16.h>
#include <stdint.h>

#define LN_EPS 1e-6f

typedef __bf16 bf16x8 __attribute__((ext_vector_type(8)));
typedef float f32x4 __attribute__((ext_vector_type(4)));

// float -> bf16 (RNE)
__device__ __forceinline__ unsigned short f2bf(float f) {
    uint32_t u = __float_as_uint(f);
    uint32_t r = (u + 0x7fffu + ((u >> 16) & 1u)) >> 16;
    return (unsigned short)r;
}

// async 16B global -> LDS (wave-uniform LDS base + lane*16 semantics)
__device__ __forceinline__ void async_copy16(const void* g, void* l) {
    const __attribute__((address_space(1))) uint32_t* gp =
        (const __attribute__((address_space(1))) uint32_t*)(uintptr_t)g;
    __attribute__((address_space(3))) uint32_t* lp =
        (__attribute__((address_space(3))) uint32_t*)(uint32_t)(uintptr_t)l;
    __builtin_amdgcn_global_load_lds(gp, lp, 16, 0, 0);
}

// ---------------- LayerNorm + cast to bf16: one WAVE per row ----------------
__global__ __launch_bounds__(256) void ln_bf16_kernel(
    const float* __restrict__ x0, const float* __restrict__ x1,
    const float* __restrict__ s0, const float* __restrict__ b0,
    const float* __restrict__ s1, const float* __restrict__ b1,
    unsigned short* __restrict__ y0, unsigned short* __restrict__ y1, int H)
{
    int wave = threadIdx.x >> 6, lane = threadIdx.x & 63;
    int row = blockIdx.x * 4 + wave;
    int prob = blockIdx.y;
    const float* x = (prob ? x1 : x0) + (size_t)row * H;
    const float* s = prob ? s1 : s0;
    const float* b = prob ? b1 : b0;
    unsigned short* y = (prob ? y1 : y0) + (size_t)row * H;

    float4 v[16];
    float sum = 0.f, sq = 0.f;
#pragma unroll
    for (int g = 0; g < 16; ++g) {
        v[g] = ((const float4*)x)[lane + 64 * g];
        sum += v[g].x + v[g].y + v[g].z + v[g].w;
        sq  += v[g].x * v[g].x + v[g].y * v[g].y + v[g].z * v[g].z + v[g].w * v[g].w;
    }
#pragma unroll
    for (int off = 32; off > 0; off >>= 1) {
        sum += __shfl_xor(sum, off, 64);
        sq  += __shfl_xor(sq, off, 64);
    }
    float mu = sum * (1.0f / 4096.0f);
    float var = sq * (1.0f / 4096.0f) - mu * mu;
    float rstd = rsqrtf(var + LN_EPS);

#pragma unroll
    for (int g = 0; g < 16; ++g) {
        int i4 = lane + 64 * g;
        float4 sc = ((const float4*)s)[i4];
        float4 bi = ((const float4*)b)[i4];
        ushort4 o;
        o.x = f2bf((v[g].x - mu) * rstd * sc.x + bi.x);
        o.y = f2bf((v[g].y - mu) * rstd * sc.y + bi.y);
        o.z = f2bf((v[g].z - mu) * rstd * sc.z + bi.z);
        o.w = f2bf((v[g].w - mu) * rstd * sc.w + bi.w);
        ((ushort4*)y)[i4] = o;
    }
}

// ---------------- cast + transpose W (K x N fp32) -> Wt (N x K bf16) ----------------
__global__ __launch_bounds__(256) void cast_transpose_kernel(
    const float* __restrict__ w0, const float* __restrict__ w1,
    unsigned short* __restrict__ o0, unsigned short* __restrict__ o1,
    int K, int N)
{
    int prob = blockIdx.z;
    const float* w = prob ? w1 : w0;
    unsigned short* o = prob ? o1 : o0;
    __shared__ unsigned short tile[32][33];
    int tx = threadIdx.x & 31;
    int ty = threadIdx.x >> 5;
    int n0 = blockIdx.x * 32;
    int k0 = blockIdx.y * 32;
#pragma unroll
    for (int i = 0; i < 4; ++i) {
        int k = ty + 8 * i;
        tile[k][tx] = f2bf(w[(size_t)(k0 + k) * N + n0 + tx]);
    }
    __syncthreads();
#pragma unroll
    for (int i = 0; i < 4; ++i) {
        int n = ty + 8 * i;
        o[(size_t)(n0 + n) * K + k0 + tx] = tile[tx][n];
    }
}

// ---------------- bf16 GEMM: out[M,N] = A[M,K] * Wt[N,K]^T + bias ----------------
// Round-0 proven geometry (128x128x64 tiles, 256 threads, 4 waves, grid 1024,
// XCD-aware swizzle, chunk-XOR LDS swizzle) with ONE change: double-buffered LDS
// (64 KiB total = the documented per-block limit) + next-tile global_load_lds
// issued before the current tile's compute. One __syncthreads per K-tile
// (implicit vmcnt+lgkm drain) is the cross-iteration fence.
#define BM 128
#define BN 128
#define BK 64

__global__ __launch_bounds__(256) void gemm_bf16_kernel(
    const unsigned short* __restrict__ A0, const unsigned short* __restrict__ A1,
    const unsigned short* __restrict__ W0, const unsigned short* __restrict__ W1,
    const float* __restrict__ bias0, const float* __restrict__ bias1,
    float* __restrict__ out0, float* __restrict__ out1,
    int M, int N, int K)
{
    // XCD-aware decode: xcd = id&7 owns m-tiles [xcd*8, xcd*8+8); n varies fastest.
    int id = blockIdx.x;
    int xcd = id & 7;
    int l = id >> 3;
    int prob = l >> 6;
    int rem = l & 63;
    int mt = xcd * 8 + (rem >> 3);
    int nt = rem & 7;

    const unsigned short* A = prob ? A1 : A0;
    const unsigned short* W = prob ? W1 : W0;
    const float* bias = prob ? bias1 : bias0;
    float* out = prob ? out1 : out0;

    __shared__ unsigned short As[2 * BM * BK];  // 32 KiB, double-buffered
    __shared__ unsigned short Bs[2 * BM * BK];  // 32 KiB

    int t = threadIdx.x;
    int wave = t >> 6, lane = t & 63;
    int quad = lane >> 4, r16 = lane & 15;
    int wm = wave >> 1, wn = wave & 1;
    int kx = r16 & 7;  // row&7 for all fragment rows this lane touches

    int tile_m = mt * BM;
    int tile_n = nt * BN;

    // staging: LDS slot (row, kb) receives GLOBAL k-chunk kb ^ (row&7).
    const unsigned short* ga[4];
    const unsigned short* gb[4];
    uint32_t lb[4];
#pragma unroll
    for (int q = 0; q < 4; ++q) {
        int cc = q * 256 + t;
        int row = cc >> 3, kb = cc & 7;
        int kbg = kb ^ (row & 7);
        ga[q] = A + (size_t)(tile_m + row) * K + kbg * 8;
        gb[q] = W + (size_t)(tile_n + row) * K + kbg * 8;
        lb[q] = (uint32_t)(q * 256 + wave * 64) * 16;  // wave-uniform byte base
    }

    f32x4 acc[4][4] = {};

    // prologue: stage K-tile 0 into buffer 0; __syncthreads drains vmcnt.
#pragma unroll
    for (int q = 0; q < 4; ++q) {
        async_copy16(ga[q], (char*)As + lb[q]);
        async_copy16(gb[q], (char*)Bs + lb[q]);
    }
    __syncthreads();

    const int NTILES = K >> 6;
    for (int kt = 0; kt < NTILES; ++kt) {
        const int cur = kt & 1;
        const unsigned short* cA = As + cur * (BM * BK);
        const unsigned short* cB = Bs + cur * (BM * BK);

        // issue next-tile staging FIRST so loads fly under this tile's MFMAs
        if (kt + 1 < NTILES) {
            const int ko = (kt + 1) << 6;
            char* dA = (char*)As + (cur ^ 1) * (BM * BK * 2);
            char* dB = (char*)Bs + (cur ^ 1) * (BM * BK * 2);
#pragma unroll
            for (int q = 0; q < 4; ++q) {
                async_copy16(ga[q] + ko, dA + lb[q]);
                async_copy16(gb[q] + ko, dB + lb[q]);
            }
        }

#pragma unroll
        for (int s = 0; s < 2; ++s) {
            bf16x8 af[4], bfr[4];
#pragma unroll
            for (int i = 0; i < 4; ++i) {
                int ka = (s * 4 + quad) ^ kx;  // slot holding global chunk s*4+quad
                af[i]  = *(const bf16x8*)(cA + (wm * 64 + i * 16 + r16) * 64 + ka * 8);
                bfr[i] = *(const bf16x8*)(cB + (wn * 64 + i * 16 + r16) * 64 + ka * 8);
            }
#pragma unroll
            for (int i = 0; i < 4; ++i)
#pragma unroll
                for (int j = 0; j < 4; ++j)
                    acc[i][j] = __builtin_amdgcn_mfma_f32_16x16x32_bf16(af[i], bfr[j], acc[i][j], 0, 0, 0);
        }

        // one full drain + barrier per K-tile
        __syncthreads();
    }

    // epilogue: C mapping col=lane&15, row=quad*4+reg
#pragma unroll
    for (int j = 0; j < 4; ++j) {
        int col = tile_n + wn * 64 + j * 16 + r16;
        float bj = bias[col];
#pragma unroll
        for (int i = 0; i < 4; ++i) {
            int row = tile_m + wm * 64 + i * 16 + quad * 4;
#pragma unroll
            for (int r = 0; r < 4; ++r)
                out[(size_t)(row + r) * N + col] = acc[i][j][r] + bj;
        }
    }
}

extern "C" void kernel_launch(void* const* d_in, const int* in_sizes, int n_in,
                              void* d_out, int out_size, void* d_ws, size_t ws_size,
                              hipStream_t stream) {
    const float* xv = (const float*)d_in[0];
    const float* xt = (const float*)d_in[1];
    const float* sv = (const float*)d_in[2];
    const float* bv = (const float*)d_in[3];
    const float* wv = (const float*)d_in[4];
    const float* biasv = (const float*)d_in[5];
    const float* st = (const float*)d_in[6];
    const float* bt = (const float*)d_in[7];
    const float* wt = (const float*)d_in[8];
    const float* biast = (const float*)d_in[9];
    float* out = (float*)d_out;

    const int B = 2, S = 4096, H = 4096, P = 1024;
    const int M = B * S;  // 8192
    float* outv = out;
    float* outt = out + (size_t)M * P;

    size_t xnBytes = (size_t)M * H * 2;  // 64 MiB per problem
    size_t wtBytes = (size_t)P * H * 2;  // 8 MiB per problem
    char* ws = (char*)d_ws;

    if (ws_size >= 2 * xnBytes + 2 * wtBytes) {
        unsigned short* Xv = (unsigned short*)(ws);
        unsigned short* Xt = (unsigned short*)(ws + xnBytes);
        unsigned short* Wv = (unsigned short*)(ws + 2 * xnBytes);
        unsigned short* Wt = (unsigned short*)(ws + 2 * xnBytes + wtBytes);
        ln_bf16_kernel<<<dim3(M / 4, 2), 256, 0, stream>>>(xv, xt, sv, bv, st, bt, Xv, Xt, H);
        cast_transpose_kernel<<<dim3(P / 32, H / 32, 2), 256, 0, stream>>>(wv, wt, Wv, Wt, H, P);
        gemm_bf16_kernel<<<dim3(1024), 256, 0, stream>>>(
            Xv, Xt, Wv, Wt, biasv, biast, outv, outt, M, P, H);
    } else {
        unsigned short* X  = (unsigned short*)(ws);
        unsigned short* Wb = (unsigned short*)(ws + xnBytes);
        ln_bf16_kernel<<<dim3(M / 4, 1), 256, 0, stream>>>(xv, xv, sv, bv, sv, bv, X, X, H);
        cast_transpose_kernel<<<dim3(P / 32, H / 32, 1), 256, 0, stream>>>(wv, wv, Wb, Wb, H, P);
        gemm_bf16_kernel<<<dim3(512), 256, 0, stream>>>(
            X, X, Wb, Wb, biasv, biasv, outv, outv, M, P, H);
        ln_bf16_kernel<<<dim3(M / 4, 1), 256, 0, stream>>>(xt, xt, st, bt, st, bt, X, X, H);
        cast_transpose_kernel<<<dim3(P / 32, H / 32, 1), 256, 0, stream>>>(wt, wt, Wb, Wb, H, P);
        gemm_bf16_kernel<<<dim3(512), 256, 0, stream>>>(
            X, X, Wb, Wb, biast, biast, outt, outt, M, P, H);
    }
}

// Round 5
// 481.601 us; speedup vs baseline: 1.1138x; 1.0361x over previous
//
#include <hip/hip_runtime.h>
#include <hip/hip_bf16.h>
#include <stdint.h>

#define LN_EPS 1e-6f

typedef __bf16 bf16x8 __attribute__((ext_vector_type(8)));
typedef float f32x4 __attribute__((ext_vector_type(4)));

// float -> bf16 (RNE)
__device__ __forceinline__ unsigned short f2bf(float f) {
    uint32_t u = __float_as_uint(f);
    uint32_t r = (u + 0x7fffu + ((u >> 16) & 1u)) >> 16;
    return (unsigned short)r;
}

// async 16B global -> LDS (wave-uniform LDS base + lane*16 semantics)
__device__ __forceinline__ void async_copy16(const void* g, void* l) {
    const __attribute__((address_space(1))) uint32_t* gp =
        (const __attribute__((address_space(1))) uint32_t*)(uintptr_t)g;
    __attribute__((address_space(3))) uint32_t* lp =
        (__attribute__((address_space(3))) uint32_t*)(uint32_t)(uintptr_t)l;
    __builtin_amdgcn_global_load_lds(gp, lp, 16, 0, 0);
}

// ---------------- LayerNorm + cast to bf16: one WAVE per row ----------------
__global__ __launch_bounds__(256) void ln_bf16_kernel(
    const float* __restrict__ x0, const float* __restrict__ x1,
    const float* __restrict__ s0, const float* __restrict__ b0,
    const float* __restrict__ s1, const float* __restrict__ b1,
    unsigned short* __restrict__ y0, unsigned short* __restrict__ y1, int H)
{
    int wave = threadIdx.x >> 6, lane = threadIdx.x & 63;
    int row = blockIdx.x * 4 + wave;
    int prob = blockIdx.y;
    const float* x = (prob ? x1 : x0) + (size_t)row * H;
    const float* s = prob ? s1 : s0;
    const float* b = prob ? b1 : b0;
    unsigned short* y = (prob ? y1 : y0) + (size_t)row * H;

    float4 v[16];
    float sum = 0.f, sq = 0.f;
#pragma unroll
    for (int g = 0; g < 16; ++g) {
        v[g] = ((const float4*)x)[lane + 64 * g];
        sum += v[g].x + v[g].y + v[g].z + v[g].w;
        sq  += v[g].x * v[g].x + v[g].y * v[g].y + v[g].z * v[g].z + v[g].w * v[g].w;
    }
#pragma unroll
    for (int off = 32; off > 0; off >>= 1) {
        sum += __shfl_xor(sum, off, 64);
        sq  += __shfl_xor(sq, off, 64);
    }
    float mu = sum * (1.0f / 4096.0f);
    float var = sq * (1.0f / 4096.0f) - mu * mu;
    float rstd = rsqrtf(var + LN_EPS);

#pragma unroll
    for (int g = 0; g < 16; ++g) {
        int i4 = lane + 64 * g;
        float4 sc = ((const float4*)s)[i4];
        float4 bi = ((const float4*)b)[i4];
        ushort4 o;
        o.x = f2bf((v[g].x - mu) * rstd * sc.x + bi.x);
        o.y = f2bf((v[g].y - mu) * rstd * sc.y + bi.y);
        o.z = f2bf((v[g].z - mu) * rstd * sc.z + bi.z);
        o.w = f2bf((v[g].w - mu) * rstd * sc.w + bi.w);
        ((ushort4*)y)[i4] = o;
    }
}

// ---------------- cast + transpose W (K x N fp32) -> Wt (N x K bf16) ----------------
__global__ __launch_bounds__(256) void cast_transpose_kernel(
    const float* __restrict__ w0, const float* __restrict__ w1,
    unsigned short* __restrict__ o0, unsigned short* __restrict__ o1,
    int K, int N)
{
    int prob = blockIdx.z;
    const float* w = prob ? w1 : w0;
    unsigned short* o = prob ? o1 : o0;
    __shared__ unsigned short tile[32][33];
    int tx = threadIdx.x & 31;
    int ty = threadIdx.x >> 5;
    int n0 = blockIdx.x * 32;
    int k0 = blockIdx.y * 32;
#pragma unroll
    for (int i = 0; i < 4; ++i) {
        int k = ty + 8 * i;
        tile[k][tx] = f2bf(w[(size_t)(k0 + k) * N + n0 + tx]);
    }
    __syncthreads();
#pragma unroll
    for (int i = 0; i < 4; ++i) {
        int n = ty + 8 * i;
        o[(size_t)(n0 + n) * K + k0 + tx] = tile[tx][n];
    }
}

// ---------------- bf16 GEMM: out[M,N] = A[M,K] * Wt[N,K]^T + bias ----------------
// 256x128x32 tiles (staged bytes/FLOP -25% vs 128x128x64), 256 threads, 4 waves,
// per-wave 128x64 output (acc[8][4]), double-buffered LDS (48 KiB <= harness 64 KiB
// limit), global_load_lds prefetch d=1, one __syncthreads per K-tile.
// Chunk-XOR LDS swizzle: 4 chunks of 8 elems per 32-elem row.
#define BM 256
#define BN 128
#define BK 32

__global__ __launch_bounds__(256, 2) void gemm_bf16_kernel(
    const unsigned short* __restrict__ A0, const unsigned short* __restrict__ A1,
    const unsigned short* __restrict__ W0, const unsigned short* __restrict__ W1,
    const float* __restrict__ bias0, const float* __restrict__ bias1,
    float* __restrict__ out0, float* __restrict__ out1,
    int M, int N, int K)
{
    // XCD-aware decode: per problem 32 m-tiles x 8 n-tiles = 256 blocks.
    // xcd = id&7 owns m-tiles [xcd*4, xcd*4+4); n varies fastest so the 8 blocks
    // sharing an A-panel are consecutive on one XCD (A-panel L2 reuse x8).
    int id = blockIdx.x;
    int xcd = id & 7;
    int l = id >> 3;
    int prob = l >> 5;          // 32 blocks per problem per XCD
    int rem = l & 31;
    int mt = xcd * 4 + (rem >> 3);
    int nt = rem & 7;

    const unsigned short* A = prob ? A1 : A0;
    const unsigned short* W = prob ? W1 : W0;
    const float* bias = prob ? bias1 : bias0;
    float* out = prob ? out1 : out0;

    __shared__ unsigned short As[2 * BM * BK];  // 32 KiB, double-buffered
    __shared__ unsigned short Bs[2 * BN * BK];  // 16 KiB, double-buffered

    int t = threadIdx.x;
    int wave = t >> 6, lane = t & 63;
    int quad = lane >> 4, r16 = lane & 15;
    int wm = wave >> 1, wn = wave & 1;   // 2x2 wave grid -> per-wave 128x64 output
    int kx = r16 & 3;                    // row&3 for all fragment rows this lane touches

    int tile_m = mt * BM;
    int tile_n = nt * BN;

    // staging: LDS slot (row, kb) receives GLOBAL k-chunk kb ^ (row&3) (4 chunks/row).
    // A: 4 rounds of 256 threads; B: 2 rounds.
    const unsigned short* ga[4];
    const unsigned short* gb[2];
    uint32_t lba[4], lbb[2];
#pragma unroll
    for (int q = 0; q < 4; ++q) {
        int cc = q * 256 + t;
        int row = cc >> 2, kb = cc & 3;
        int kbg = kb ^ (row & 3);
        ga[q] = A + (size_t)(tile_m + row) * K + kbg * 8;
        lba[q] = (uint32_t)(q * 256 + wave * 64) * 16;  // wave-uniform byte base
    }
#pragma unroll
    for (int q = 0; q < 2; ++q) {
        int cc = q * 256 + t;
        int row = cc >> 2, kb = cc & 3;
        int kbg = kb ^ (row & 3);
        gb[q] = W + (size_t)(tile_n + row) * K + kbg * 8;
        lbb[q] = (uint32_t)(q * 256 + wave * 64) * 16;
    }

    f32x4 acc[8][4] = {};

    // prologue: stage K-tile 0 into buffer 0; __syncthreads drains vmcnt.
#pragma unroll
    for (int q = 0; q < 4; ++q) async_copy16(ga[q], (char*)As + lba[q]);
#pragma unroll
    for (int q = 0; q < 2; ++q) async_copy16(gb[q], (char*)Bs + lbb[q]);
    __syncthreads();

    const int NTILES = K >> 5;  // BK=32
    for (int kt = 0; kt < NTILES; ++kt) {
        const int cur = kt & 1;
        const unsigned short* cA = As + cur * (BM * BK);
        const unsigned short* cB = Bs + cur * (BN * BK);

        // issue next-tile staging FIRST so loads fly under this tile's MFMAs
        if (kt + 1 < NTILES) {
            const int ko = (kt + 1) << 5;
            char* dA = (char*)As + (cur ^ 1) * (BM * BK * 2);
            char* dB = (char*)Bs + (cur ^ 1) * (BN * BK * 2);
#pragma unroll
            for (int q = 0; q < 4; ++q) async_copy16(ga[q] + ko, dA + lba[q]);
#pragma unroll
            for (int q = 0; q < 2; ++q) async_copy16(gb[q] + ko, dB + lbb[q]);
        }

        // B fragments (4 n-frags), register-held across all 8 m-frags
        bf16x8 bfr[4];
#pragma unroll
        for (int j = 0; j < 4; ++j) {
            int row = wn * 64 + j * 16 + r16;
            int ka = quad ^ kx;  // slot holding global chunk `quad`
            bfr[j] = *(const bf16x8*)(cB + row * 32 + ka * 8);
        }
#pragma unroll
        for (int i = 0; i < 8; ++i) {
            int row = wm * 128 + i * 16 + r16;
            int ka = quad ^ kx;
            bf16x8 af = *(const bf16x8*)(cA + row * 32 + ka * 8);
#pragma unroll
            for (int j = 0; j < 4; ++j)
                acc[i][j] = __builtin_amdgcn_mfma_f32_16x16x32_bf16(af, bfr[j], acc[i][j], 0, 0, 0);
        }

        // one full drain + barrier per K-tile
        __syncthreads();
    }

    // epilogue: C mapping col=lane&15, row=quad*4+reg
#pragma unroll
    for (int j = 0; j < 4; ++j) {
        int col = tile_n + wn * 64 + j * 16 + r16;
        float bj = bias[col];
#pragma unroll
        for (int i = 0; i < 8; ++i) {
            int row = tile_m + wm * 128 + i * 16 + quad * 4;
#pragma unroll
            for (int r = 0; r < 4; ++r)
                out[(size_t)(row + r) * N + col] = acc[i][j][r] + bj;
        }
    }
}

extern "C" void kernel_launch(void* const* d_in, const int* in_sizes, int n_in,
                              void* d_out, int out_size, void* d_ws, size_t ws_size,
                              hipStream_t stream) {
    const float* xv = (const float*)d_in[0];
    const float* xt = (const float*)d_in[1];
    const float* sv = (const float*)d_in[2];
    const float* bv = (const float*)d_in[3];
    const float* wv = (const float*)d_in[4];
    const float* biasv = (const float*)d_in[5];
    const float* st = (const float*)d_in[6];
    const float* bt = (const float*)d_in[7];
    const float* wt = (const float*)d_in[8];
    const float* biast = (const float*)d_in[9];
    float* out = (float*)d_out;

    const int B = 2, S = 4096, H = 4096, P = 1024;
    const int M = B * S;  // 8192
    float* outv = out;
    float* outt = out + (size_t)M * P;

    size_t xnBytes = (size_t)M * H * 2;  // 64 MiB per problem
    size_t wtBytes = (size_t)P * H * 2;  // 8 MiB per problem
    char* ws = (char*)d_ws;

    if (ws_size >= 2 * xnBytes + 2 * wtBytes) {
        unsigned short* Xv = (unsigned short*)(ws);
        unsigned short* Xt = (unsigned short*)(ws + xnBytes);
        unsigned short* Wv = (unsigned short*)(ws + 2 * xnBytes);
        unsigned short* Wt = (unsigned short*)(ws + 2 * xnBytes + wtBytes);
        ln_bf16_kernel<<<dim3(M / 4, 2), 256, 0, stream>>>(xv, xt, sv, bv, st, bt, Xv, Xt, H);
        cast_transpose_kernel<<<dim3(P / 32, H / 32, 2), 256, 0, stream>>>(wv, wt, Wv, Wt, H, P);
        gemm_bf16_kernel<<<dim3(512), 256, 0, stream>>>(
            Xv, Xt, Wv, Wt, biasv, biast, outv, outt, M, P, H);
    } else {
        unsigned short* X  = (unsigned short*)(ws);
        unsigned short* Wb = (unsigned short*)(ws + xnBytes);
        ln_bf16_kernel<<<dim3(M / 4, 1), 256, 0, stream>>>(xv, xv, sv, bv, sv, bv, X, X, H);
        cast_transpose_kernel<<<dim3(P / 32, H / 32, 1), 256, 0, stream>>>(wv, wv, Wb, Wb, H, P);
        gemm_bf16_kernel<<<dim3(256), 256, 0, stream>>>(
            X, X, Wb, Wb, biasv, biasv, outv, outv, M, P, H);
        ln_bf16_kernel<<<dim3(M / 4, 1), 256, 0, stream>>>(xt, xt, st, bt, st, bt, X, X, H);
        cast_transpose_kernel<<<dim3(P / 32, H / 32, 1), 256, 0, stream>>>(wt, wt, Wb, Wb, H, P);
        gemm_bf16_kernel<<<dim3(256), 256, 0, stream>>>(
            X, X, Wb, Wb, biast, biast, outt, outt, M, P, H);
    }
}

// Round 8
// 481.231 us; speedup vs baseline: 1.1146x; 1.0008x over previous
//
#include <hip/hip_runtime.h>
#include <hip/hip_bf16.h>
#include <stdint.h>

#define LN_EPS 1e-6f

typedef __bf16 bf16x8 __attribute__((ext_vector_type(8)));
typedef float f32x4 __attribute__((ext_vector_type(4)));

// float -> bf16 (RNE)
__device__ __forceinline__ unsigned short f2bf(float f) {
    uint32_t u = __float_as_uint(f);
    uint32_t r = (u + 0x7fffu + ((u >> 16) & 1u)) >> 16;
    return (unsigned short)r;
}

// async 16B global -> LDS (wave-uniform LDS base + lane*16 semantics)
__device__ __forceinline__ void async_copy16(const void* g, void* l) {
    const __attribute__((address_space(1))) uint32_t* gp =
        (const __attribute__((address_space(1))) uint32_t*)(uintptr_t)g;
    __attribute__((address_space(3))) uint32_t* lp =
        (__attribute__((address_space(3))) uint32_t*)(uint32_t)(uintptr_t)l;
    __builtin_amdgcn_global_load_lds(gp, lp, 16, 0, 0);
}

// ---------------- LayerNorm + cast to bf16: one WAVE per row ----------------
__global__ __launch_bounds__(256) void ln_bf16_kernel(
    const float* __restrict__ x0, const float* __restrict__ x1,
    const float* __restrict__ s0, const float* __restrict__ b0,
    const float* __restrict__ s1, const float* __restrict__ b1,
    unsigned short* __restrict__ y0, unsigned short* __restrict__ y1, int H)
{
    int wave = threadIdx.x >> 6, lane = threadIdx.x & 63;
    int row = blockIdx.x * 4 + wave;
    int prob = blockIdx.y;
    const float* x = (prob ? x1 : x0) + (size_t)row * H;
    const float* s = prob ? s1 : s0;
    const float* b = prob ? b1 : b0;
    unsigned short* y = (prob ? y1 : y0) + (size_t)row * H;

    float4 v[16];
    float sum = 0.f, sq = 0.f;
#pragma unroll
    for (int g = 0; g < 16; ++g) {
        v[g] = ((const float4*)x)[lane + 64 * g];
        sum += v[g].x + v[g].y + v[g].z + v[g].w;
        sq  += v[g].x * v[g].x + v[g].y * v[g].y + v[g].z * v[g].z + v[g].w * v[g].w;
    }
#pragma unroll
    for (int off = 32; off > 0; off >>= 1) {
        sum += __shfl_xor(sum, off, 64);
        sq  += __shfl_xor(sq, off, 64);
    }
    float mu = sum * (1.0f / 4096.0f);
    float var = sq * (1.0f / 4096.0f) - mu * mu;
    float rstd = rsqrtf(var + LN_EPS);

#pragma unroll
    for (int g = 0; g < 16; ++g) {
        int i4 = lane + 64 * g;
        float4 sc = ((const float4*)s)[i4];
        float4 bi = ((const float4*)b)[i4];
        ushort4 o;
        o.x = f2bf((v[g].x - mu) * rstd * sc.x + bi.x);
        o.y = f2bf((v[g].y - mu) * rstd * sc.y + bi.y);
        o.z = f2bf((v[g].z - mu) * rstd * sc.z + bi.z);
        o.w = f2bf((v[g].w - mu) * rstd * sc.w + bi.w);
        ((ushort4*)y)[i4] = o;
    }
}

// ---------------- cast + transpose W (K x N fp32) -> Wt (N x K bf16) ----------------
// Round-5 proven version (scalar LDS accesses, 32x33 padded tile).
__global__ __launch_bounds__(256) void cast_transpose_kernel(
    const float* __restrict__ w0, const float* __restrict__ w1,
    unsigned short* __restrict__ o0, unsigned short* __restrict__ o1,
    int K, int N)
{
    int prob = blockIdx.z;
    const float* w = prob ? w1 : w0;
    unsigned short* o = prob ? o1 : o0;
    __shared__ __align__(16) unsigned short tile[32][33];
    int tx = threadIdx.x & 31;
    int ty = threadIdx.x >> 5;
    int n0 = blockIdx.x * 32;
    int k0 = blockIdx.y * 32;
#pragma unroll
    for (int i = 0; i < 4; ++i) {
        int k = ty + 8 * i;
        tile[k][tx] = f2bf(w[(size_t)(k0 + k) * N + n0 + tx]);
    }
    __syncthreads();
#pragma unroll
    for (int i = 0; i < 4; ++i) {
        int n = ty + 8 * i;
        o[(size_t)(n0 + n) * K + k0 + tx] = tile[tx][n];
    }
}

// ---------------- bf16 GEMM: out[M,N] = A[M,K] * Wt[N,K]^T + bias ----------------
// 256x128x32 tiles, 256 threads, 4 waves, per-wave 128x64 output (acc[8][4]),
// double-buffered LDS (48 KiB), global_load_lds prefetch d=1, one __syncthreads
// per K-tile.
// LDS swizzle: chunk kb of row r stored at slot kb ^ ((r>>1)&3).  With 64B rows,
// slot%8 = 4*(r&1) + (kb ^ ((r>>1)&3)) -> lanes r16=0..7 of a quad cover all 8
// bank-groups (r16=8..15 alias 2-way = free).
// MFMA operands SWAPPED (bfr first): D[n][m] with lane mapping m=r16 (col),
// n=quad*4+reg (row) -> each lane holds 4 consecutive n -> dwordx4 epilogue.
#define BM 256
#define BN 128
#define BK 32

__global__ __launch_bounds__(256, 2) void gemm_bf16_kernel(
    const unsigned short* __restrict__ A0, const unsigned short* __restrict__ A1,
    const unsigned short* __restrict__ W0, const unsigned short* __restrict__ W1,
    const float* __restrict__ bias0, const float* __restrict__ bias1,
    float* __restrict__ out0, float* __restrict__ out1,
    int M, int N, int K)
{
    // XCD-aware decode: per problem 32 m-tiles x 8 n-tiles = 256 blocks.
    int id = blockIdx.x;
    int xcd = id & 7;
    int l = id >> 3;
    int prob = l >> 5;          // 32 blocks per problem per XCD
    int rem = l & 31;
    int mt = xcd * 4 + (rem >> 3);
    int nt = rem & 7;

    const unsigned short* A = prob ? A1 : A0;
    const unsigned short* W = prob ? W1 : W0;
    const float* bias = prob ? bias1 : bias0;
    float* out = prob ? out1 : out0;

    __shared__ __align__(16) unsigned short As[2 * BM * BK];  // 32 KiB, double-buffered
    __shared__ __align__(16) unsigned short Bs[2 * BN * BK];  // 16 KiB, double-buffered

    int t = threadIdx.x;
    int wave = t >> 6, lane = t & 63;
    int quad = lane >> 4, r16 = lane & 15;
    int wm = wave >> 1, wn = wave & 1;   // 2x2 wave grid -> per-wave 128x64 output
    int kx = (r16 >> 1) & 3;             // (row>>1)&3 for all fragment rows this lane touches

    int tile_m = mt * BM;
    int tile_n = nt * BN;

    // staging: LDS slot (row, kb) receives GLOBAL k-chunk kb ^ ((row>>1)&3).
    const unsigned short* ga[4];
    const unsigned short* gb[2];
    uint32_t lba[4], lbb[2];
#pragma unroll
    for (int q = 0; q < 4; ++q) {
        int cc = q * 256 + t;
        int row = cc >> 2, kb = cc & 3;
        int kbg = kb ^ ((row >> 1) & 3);
        ga[q] = A + (size_t)(tile_m + row) * K + kbg * 8;
        lba[q] = (uint32_t)(q * 256 + wave * 64) * 16;  // wave-uniform byte base
    }
#pragma unroll
    for (int q = 0; q < 2; ++q) {
        int cc = q * 256 + t;
        int row = cc >> 2, kb = cc & 3;
        int kbg = kb ^ ((row >> 1) & 3);
        gb[q] = W + (size_t)(tile_n + row) * K + kbg * 8;
        lbb[q] = (uint32_t)(q * 256 + wave * 64) * 16;
    }

    f32x4 acc[8][4] = {};

    // prologue: stage K-tile 0 into buffer 0; __syncthreads drains vmcnt.
#pragma unroll
    for (int q = 0; q < 4; ++q) async_copy16(ga[q], (char*)As + lba[q]);
#pragma unroll
    for (int q = 0; q < 2; ++q) async_copy16(gb[q], (char*)Bs + lbb[q]);
    __syncthreads();

    const int NTILES = K >> 5;  // BK=32
    for (int kt = 0; kt < NTILES; ++kt) {
        const int cur = kt & 1;
        const unsigned short* cA = As + cur * (BM * BK);
        const unsigned short* cB = Bs + cur * (BN * BK);

        // issue next-tile staging FIRST so loads fly under this tile's MFMAs
        if (kt + 1 < NTILES) {
            const int ko = (kt + 1) << 5;
            char* dA = (char*)As + (cur ^ 1) * (BM * BK * 2);
            char* dB = (char*)Bs + (cur ^ 1) * (BN * BK * 2);
#pragma unroll
            for (int q = 0; q < 4; ++q) async_copy16(ga[q] + ko, dA + lba[q]);
#pragma unroll
            for (int q = 0; q < 2; ++q) async_copy16(gb[q] + ko, dB + lbb[q]);
        }

        // B fragments (4 n-frags), register-held across all 8 m-frags
        bf16x8 bfr[4];
#pragma unroll
        for (int j = 0; j < 4; ++j) {
            int row = wn * 64 + j * 16 + r16;
            int ka = quad ^ kx;  // slot holding global chunk `quad`
            bfr[j] = *(const bf16x8*)(cB + row * 32 + ka * 8);
        }
#pragma unroll
        for (int i = 0; i < 8; ++i) {
            int row = wm * 128 + i * 16 + r16;
            int ka = quad ^ kx;
            bf16x8 af = *(const bf16x8*)(cA + row * 32 + ka * 8);
#pragma unroll
            for (int j = 0; j < 4; ++j)
                acc[i][j] = __builtin_amdgcn_mfma_f32_16x16x32_bf16(bfr[j], af, acc[i][j], 0, 0, 0);
        }

        // one full drain + barrier per K-tile
        __syncthreads();
    }

    // epilogue: swapped-operand C mapping -> m = r16, n = quad*4 + reg.
    // Each lane stores float4 (4 consecutive n) per (i,j).
#pragma unroll
    for (int i = 0; i < 8; ++i) {
        size_t row = (size_t)(tile_m + wm * 128 + i * 16 + r16);
        float* orow = out + row * N;
#pragma unroll
        for (int j = 0; j < 4; ++j) {
            int ncol = tile_n + wn * 64 + j * 16 + quad * 4;
            f32x4 v = acc[i][j] + *(const f32x4*)(bias + ncol);
            *(f32x4*)(orow + ncol) = v;
        }
    }
}

extern "C" void kernel_launch(void* const* d_in, const int* in_sizes, int n_in,
                              void* d_out, int out_size, void* d_ws, size_t ws_size,
                              hipStream_t stream) {
    const float* xv = (const float*)d_in[0];
    const float* xt = (const float*)d_in[1];
    const float* sv = (const float*)d_in[2];
    const float* bv = (const float*)d_in[3];
    const float* wv = (const float*)d_in[4];
    const float* biasv = (const float*)d_in[5];
    const float* st = (const float*)d_in[6];
    const float* bt = (const float*)d_in[7];
    const float* wt = (const float*)d_in[8];
    const float* biast = (const float*)d_in[9];
    float* out = (float*)d_out;

    const int B = 2, S = 4096, H = 4096, P = 1024;
    const int M = B * S;  // 8192
    float* outv = out;
    float* outt = out + (size_t)M * P;

    size_t xnBytes = (size_t)M * H * 2;  // 64 MiB per problem
    size_t wtBytes = (size_t)P * H * 2;  // 8 MiB per problem
    char* ws = (char*)d_ws;

    if (ws_size >= 2 * xnBytes + 2 * wtBytes) {
        unsigned short* Xv = (unsigned short*)(ws);
        unsigned short* Xt = (unsigned short*)(ws + xnBytes);
        unsigned short* Wv = (unsigned short*)(ws + 2 * xnBytes);
        unsigned short* Wt = (unsigned short*)(ws + 2 * xnBytes + wtBytes);
        ln_bf16_kernel<<<dim3(M / 4, 2), 256, 0, stream>>>(xv, xt, sv, bv, st, bt, Xv, Xt, H);
        cast_transpose_kernel<<<dim3(P / 32, H / 32, 2), 256, 0, stream>>>(wv, wt, Wv, Wt, H, P);
        gemm_bf16_kernel<<<dim3(512), 256, 0, stream>>>(
            Xv, Xt, Wv, Wt, biasv, biast, outv, outt, M, P, H);
    } else {
        unsigned short* X  = (unsigned short*)(ws);
        unsigned short* Wb = (unsigned short*)(ws + xnBytes);
        ln_bf16_kernel<<<dim3(M / 4, 1), 256, 0, stream>>>(xv, xv, sv, bv, sv, bv, X, X, H);
        cast_transpose_kernel<<<dim3(P / 32, H / 32, 1), 256, 0, stream>>>(wv, wv, Wb, Wb, H, P);
        gemm_bf16_kernel<<<dim3(256), 256, 0, stream>>>(
            X, X, Wb, Wb, biasv, biasv, outv, outv, M, P, H);
        ln_bf16_kernel<<<dim3(M / 4, 1), 256, 0, stream>>>(xt, xt, st, bt, st, bt, X, X, H);
        cast_transpose_kernel<<<dim3(P / 32, H / 32, 1), 256, 0, stream>>>(wt, wt, Wb, Wb, H, P);
        gemm_bf16_kernel<<<dim3(256), 256, 0, stream>>>(
            X, X, Wb, Wb, biast, biast, outt, outt, M, P, H);
    }
}